// Round 23
// baseline (136.560 us; speedup 1.0000x reference)
//
#include <hip/hip_runtime.h>
#include <hip/hip_bf16.h>

#define TSEQ 2048
#define CDIM 1024
#define NH 16
#define HS 64

typedef __attribute__((ext_vector_type(8))) short bf16x8;
typedef __attribute__((ext_vector_type(4))) float f32x4;
typedef __attribute__((ext_vector_type(16))) float f32x16;

__device__ inline void gload16(const void* g, void* l) {
    __builtin_amdgcn_global_load_lds((const __attribute__((address_space(1))) void*)g,
                                     (__attribute__((address_space(3))) void*)l, 16, 0, 0);
}
__device__ inline void gload4(const void* g, void* l) {
    __builtin_amdgcn_global_load_lds((const __attribute__((address_space(1))) void*)g,
                                     (__attribute__((address_space(3))) void*)l, 4, 0, 0);
}

__device__ inline unsigned packbf(float a, float b) {
    union { __hip_bfloat162 h; unsigned u; } cv;
    cv.h = __float22bfloat162_rn(make_float2(a, b));
    return cv.u;
}

// ---------- elementwise f32 -> bf16 ----------
__global__ __launch_bounds__(256)
void conv_bf16(const float* __restrict__ in, __hip_bfloat16* __restrict__ out, int n) {
    int i = (blockIdx.x * 256 + threadIdx.x) * 4;
    if (i + 3 < n) {
        float4 v = *(const float4*)(in + i);
        union { ushort4 u; __hip_bfloat16 h[4]; } o;
        o.h[0] = __float2bfloat16(v.x);
        o.h[1] = __float2bfloat16(v.y);
        o.h[2] = __float2bfloat16(v.z);
        o.h[3] = __float2bfloat16(v.w);
        *(ushort4*)((unsigned short*)out + i) = o.u;
    }
}

// ---------- b2 * log2(e) precompute (bias folded into MFMA C-init) ----------
__global__ __launch_bounds__(256)
void b2_log2e(const float* __restrict__ b2, float* __restrict__ bl, int n) {
    int i = blockIdx.x * 256 + threadIdx.x;
    if (i < n) bl[i] = b2[i] * 1.44269504f;
}

// ---------- tiled transpose (+convert) : in [R][C] f32 -> out [C][R] bf16 ----------
__global__ __launch_bounds__(256)
void transpose_to_bf16(const float* __restrict__ in, __hip_bfloat16* __restrict__ out,
                       int R, int C) {
    __shared__ float t[32][33];
    const int tx = threadIdx.x & 31, ty = threadIdx.x >> 5;  // 32 x 8
    const int r0 = blockIdx.y * 32, c0 = blockIdx.x * 32;
    #pragma unroll
    for (int i = 0; i < 32; i += 8)
        t[ty + i][tx] = in[(size_t)(r0 + ty + i) * C + c0 + tx];
    __syncthreads();
    #pragma unroll
    for (int i = 0; i < 32; i += 8)
        out[(size_t)(c0 + ty + i) * R + r0 + tx] = __float2bfloat16(t[tx][ty + i]);
}

// ---------- fused 3x 1024x1024 transpose (W1, Wv, Wp) ----------
__global__ __launch_bounds__(256)
void transpose3_to_bf16(const float* __restrict__ W1, const float* __restrict__ Wv,
                        const float* __restrict__ Wp, __hip_bfloat16* __restrict__ o1,
                        __hip_bfloat16* __restrict__ o2, __hip_bfloat16* __restrict__ o3) {
    __shared__ float t[32][33];
    const float* in = blockIdx.z == 0 ? W1 : (blockIdx.z == 1 ? Wv : Wp);
    __hip_bfloat16* out = blockIdx.z == 0 ? o1 : (blockIdx.z == 1 ? o2 : o3);
    const int tx = threadIdx.x & 31, ty = threadIdx.x >> 5;
    const int r0 = blockIdx.y * 32, c0 = blockIdx.x * 32;
    #pragma unroll
    for (int i = 0; i < 32; i += 8)
        t[ty + i][tx] = in[(size_t)(r0 + ty + i) * CDIM + c0 + tx];
    __syncthreads();
    #pragma unroll
    for (int i = 0; i < 32; i += 8)
        out[(size_t)(c0 + ty + i) * CDIM + r0 + tx] = __float2bfloat16(t[tx][ty + i]);
}

// ---------- fused QV GEMM: [H | Vblk] = x @ [W1 | Wv] ----------
// H scaled by log2(e) so attention can use native exp2 directly.
// V written to BLOCKED layout Vblk[h][b][kt][d][64] with sigma (swap t-bits
// 2,3) applied within each 64-panel so the attention kernel's PV B-operand
// lines up with direct-packed P fragments (no shfl).
__global__ __launch_bounds__(256, 2)
void gemm_qv(const __hip_bfloat16* __restrict__ X, const __hip_bfloat16* __restrict__ W,
             const float* __restrict__ bw1, const float* __restrict__ b1,
             const float* __restrict__ bv, __hip_bfloat16* __restrict__ Hb,
             __hip_bfloat16* __restrict__ Vblk, int M)
{
    __shared__ __align__(16) __hip_bfloat16 As[128 * 32];
    __shared__ __align__(16) __hip_bfloat16 Bs[128 * 32];
    const int tid = threadIdx.x, wave = tid >> 6, lane = tid & 63;
    const int wr = wave >> 1, wc = wave & 1, l15 = lane & 15, l4 = lane >> 4;
    const int m0 = blockIdx.y * 128, n0 = blockIdx.x * 128;
    const int K = CDIM;
    const int Bb = M >> 11;                       // batches (T=2048)
    const int srow = wave * 32 + (lane >> 2), scol = (lane & 3) * 8;
    const __hip_bfloat16* xg = X + (size_t)(m0 + srow) * K + scol;
    const __hip_bfloat16* wg = W + (size_t)(n0 + srow) * K + scol;
    __hip_bfloat16* la = &As[wave * 32 * 32];
    __hip_bfloat16* lb = &Bs[wave * 32 * 32];

    f32x4 acc[4][4] = {};
    for (int k0 = 0; k0 < K; k0 += 32) {
        __syncthreads();
        gload16(xg + k0, la);
        gload16(xg + k0 + (size_t)16 * K, la + 16 * 32);
        gload16(wg + k0, lb);
        gload16(wg + k0 + (size_t)16 * K, lb + 16 * 32);
        __syncthreads();
        bf16x8 af[4], bfr[4];
        #pragma unroll
        for (int f = 0; f < 4; f++) af[f]  = *(const bf16x8*)&As[(wr * 64 + f * 16 + l15) * 32 + l4 * 8];
        #pragma unroll
        for (int f = 0; f < 4; f++) bfr[f] = *(const bf16x8*)&Bs[(wc * 64 + f * 16 + l15) * 32 + l4 * 8];
        #pragma unroll
        for (int fr = 0; fr < 4; fr++)
            #pragma unroll
            for (int fc = 0; fc < 4; fc++)
                acc[fr][fc] = __builtin_amdgcn_mfma_f32_16x16x32_bf16(af[fr], bfr[fc], acc[fr][fc], 0, 0, 0);
    }

    const bool isH = (n0 < CDIM);
    const int sl4 = ((l4 & 1) << 1) | (l4 >> 1);   // sigma: swap t-bits 2,3
    if (isH) {
        #pragma unroll
        for (int fc = 0; fc < 4; fc++) {
            const int col = n0 + wc * 64 + fc * 16 + l15;
            const float bias = bw1[col] + b1[col & (HS - 1)];
            #pragma unroll
            for (int fr = 0; fr < 4; fr++)
                #pragma unroll
                for (int r = 0; r < 4; r++) {
                    const int row = m0 + wr * 64 + fr * 16 + l4 * 4 + r;
                    const float hv = fmaxf(acc[fr][fc][r] + bias, 0.f) * 1.44269504f;
                    Hb[(size_t)row * CDIM + col] = __float2bfloat16(hv);
                }
        }
    } else {
        const int mt = m0 + wr * 64;
        const int bb = mt >> 11;                   // batch
        const int ktb = (mt & (TSEQ - 1)) >> 6;    // k-tile index
        const int hh = ((n0 - CDIM) + wc * 64) >> 6;  // head
        __hip_bfloat16* tile = Vblk + (((size_t)hh * Bb + bb) * (TSEQ / 64) + ktb) * (HS * 64);
        #pragma unroll
        for (int fc = 0; fc < 4; fc++) {
            const int d = fc * 16 + l15;
            const int c2 = hh * HS + d;
            const float bias = bv[c2];
            #pragma unroll
            for (int fr = 0; fr < 4; fr++) {
                const int tl = fr * 16 + sl4 * 4;  // sigma'd t within panel
                union { ushort4 u; __hip_bfloat16 h[4]; } o;
                #pragma unroll
                for (int r = 0; r < 4; r++) o.h[r] = __float2bfloat16(acc[fr][fc][r] + bias);
                *(ushort4*)(tile + (size_t)d * 64 + tl) = o.u;
            }
        }
    }
}

// ---------- projection GEMM: out = Y @ Wp + bp (f32 out) ----------
__global__ __launch_bounds__(256, 2)
void gemm_proj(const __hip_bfloat16* __restrict__ X, const __hip_bfloat16* __restrict__ Wt,
               const float* __restrict__ bN, float* __restrict__ Out, int M)
{
    __shared__ __align__(16) __hip_bfloat16 As[128 * 32];
    __shared__ __align__(16) __hip_bfloat16 Bs[128 * 32];
    const int tid = threadIdx.x, wave = tid >> 6, lane = tid & 63;
    const int wr = wave >> 1, wc = wave & 1, l15 = lane & 15, l4 = lane >> 4;
    const int m0 = blockIdx.y * 128, n0 = blockIdx.x * 128;
    const int K = CDIM;
    const int srow = wave * 32 + (lane >> 2), scol = (lane & 3) * 8;
    const __hip_bfloat16* xg = X + (size_t)(m0 + srow) * K + scol;
    const __hip_bfloat16* wg = Wt + (size_t)(n0 + srow) * K + scol;
    __hip_bfloat16* la = &As[wave * 32 * 32];
    __hip_bfloat16* lb = &Bs[wave * 32 * 32];

    f32x4 acc[4][4] = {};
    for (int k0 = 0; k0 < K; k0 += 32) {
        __syncthreads();
        gload16(xg + k0, la);
        gload16(xg + k0 + (size_t)16 * K, la + 16 * 32);
        gload16(wg + k0, lb);
        gload16(wg + k0 + (size_t)16 * K, lb + 16 * 32);
        __syncthreads();
        bf16x8 af[4], bfr[4];
        #pragma unroll
        for (int f = 0; f < 4; f++) af[f]  = *(const bf16x8*)&As[(wr * 64 + f * 16 + l15) * 32 + l4 * 8];
        #pragma unroll
        for (int f = 0; f < 4; f++) bfr[f] = *(const bf16x8*)&Bs[(wc * 64 + f * 16 + l15) * 32 + l4 * 8];
        #pragma unroll
        for (int fr = 0; fr < 4; fr++)
            #pragma unroll
            for (int fc = 0; fc < 4; fc++)
                acc[fr][fc] = __builtin_amdgcn_mfma_f32_16x16x32_bf16(af[fr], bfr[fc], acc[fr][fc], 0, 0, 0);
    }

    #pragma unroll
    for (int fc = 0; fc < 4; fc++) {
        const int col = n0 + wc * 64 + fc * 16 + l15;
        const float bias = bN[col];
        #pragma unroll
        for (int fr = 0; fr < 4; fr++)
            #pragma unroll
            for (int r = 0; r < 4; r++) {
                const int row = m0 + wr * 64 + fr * 16 + l4 * 4 + r;
                Out[(size_t)row * CDIM + col] = acc[fr][fc][r] + bias;
            }
    }
}

// ---------- fused synthesizer attention v19: equal-cost pair blocks ----------
// Block = 512 threads (8 waves) = q-tile PAIR (pr, 15-pr) of one (h,batch):
// wave w owns 32 q-rows of tile A=pr (w even) or B=15-pr (w odd), slot w>>1.
// Both tiles share the SAME K[kt] and V[kt] -> one ring serves all 8 waves
// (per wave per stage: 1 K gload16 + 1 V gload16 + 1 bias gload4 = uniform 3).
// Grid 8x16x2 = 256 = exactly 1 block/CU; per-block work = 132 wave-subtiles
// by construction -> zero tail/imbalance. Ring-3, depth-2, vmcnt(3) protocol
// (v13-proven). Per-wave body identical to v13.
#define STAGEKV(KT, BUF) do {                                                   \
    gload16(kg + (size_t)(KT) * (64 * HS), &Ks[BUF][(w * 8) * 64]);             \
    gload16(vg + (size_t)(KT) * (HS * 64), &Vs[BUF][(w * 8) * 64]);             \
    gload4(blg + (size_t)(KT) * 64, &blr[BUF][0]);                              \
} while (0)

__global__ __launch_bounds__(512, 1)
void attn_mfma19(const __hip_bfloat16* __restrict__ H, const __hip_bfloat16* __restrict__ w2t,
                 const __hip_bfloat16* __restrict__ Vblk, const float* __restrict__ bl,
                 __hip_bfloat16* __restrict__ Y, int M)
{
    __shared__ __align__(16) __hip_bfloat16 Ks[3][64 * 64];  // [t][hs], swizzled
    __shared__ __align__(16) __hip_bfloat16 Vs[3][64 * 64];  // [d][t sigma], swizzled
    __shared__ __align__(16) float blr[3][64];               // bias ring
    __shared__ float Ls[8 * 32];

    const int tid = threadIdx.x;
    const int w = tid >> 6, lane = tid & 63;
    const int l31 = lane & 31, hi = lane >> 5;
    const int pr = blockIdx.x;               // pair index 0..7
    const int h = blockIdx.y, b = blockIdx.z;
    const int qtile = (w & 1) ? (15 - pr) : pr;
    const int qw = qtile * 128 + (w >> 1) * 32;   // this wave's first q row
    const int swz = l31 & 7;
    const int Bb = M >> 11;

    // staging geometry: wave w stages rows w*8 .. w*8+7 of each K and V tile
    const int srr = lane >> 3, spc = lane & 7;
    const int sr = w * 8 + srr;
    const int sc = (spc ^ srr) * 8;          // pre-XOR source chunk ((sr&7)==srr)
    const __hip_bfloat16* kg = w2t + (size_t)sr * HS + sc;
    const __hip_bfloat16* vpan = Vblk + (((size_t)h * Bb + b) * (TSEQ / 64)) * (HS * 64);
    const __hip_bfloat16* vg = vpan + (size_t)sr * 64 + sc;
    const float* blg = bl + lane;            // per-lane f32 source (width-4 stage)

    // H fragments (B-operand: col=lane&31=q, k=hi*8+j), in registers
    bf16x8 hf[4];
    {
        const size_t row = (size_t)(b * TSEQ + qw + l31);
        #pragma unroll
        for (int kk = 0; kk < 4; kk++)
            hf[kk] = *(const bf16x8*)(H + row * CDIM + h * HS + kk * 16 + hi * 8);
    }

    f32x16 yacc[2] = {};
    float lsum = 0.f;
    const int lastkt = (qw + 31) >> 6;                 // this wave's causal bound
    const int ntile = 2 * (15 - pr) + 2;               // block bound (heaviest wave)

    STAGEKV(0, 0);
    STAGEKV(1, 1);

    for (int kt = 0; kt < ntile; kt++) {
        const int k0 = kt * 64;
        if (kt + 1 < ntile) asm volatile("s_waitcnt vmcnt(3)" ::: "memory");
        else                asm volatile("s_waitcnt vmcnt(0)" ::: "memory");
        __builtin_amdgcn_s_barrier();      // all waves' S(kt) landed
        __builtin_amdgcn_sched_barrier(0);
        if (kt + 2 < ntile) STAGEKV(kt + 2, (kt + 2) % 3);  // depth-2 prefetch
        if (kt <= lastkt) {
            const int buf = kt % 3;
            const bool nomask = (k0 + 63 <= qw);
            bf16x8 pa[4];
            #pragma unroll
            for (int tf = 0; tf < 2; tf++) {
                // C-init = bias*log2e from the ring (broadcast, conflict-free)
                f32x16 st;
                #pragma unroll
                for (int g = 0; g < 4; g++) {
                    float4 blv = *(const float4*)&blr[buf][tf * 32 + g * 8 + hi * 4];
                    st[g * 4 + 0] = blv.x; st[g * 4 + 1] = blv.y;
                    st[g * 4 + 2] = blv.z; st[g * 4 + 3] = blv.w;
                }
                #pragma unroll
                for (int kk = 0; kk < 4; kk++) {
                    const int cs = (kk * 2 + hi) ^ swz;
                    bf16x8 kf = *(const bf16x8*)((const char*)&Ks[buf][0] + (tf * 32 + l31) * 128 + cs * 16);
                    st = __builtin_amdgcn_mfma_f32_32x32x16_bf16(kf, hf[kk], st, 0, 0, 0);
                }
                const int qg = qw + l31;
                float p[16];
                #pragma unroll
                for (int r = 0; r < 16; r++) {
                    float e = __builtin_amdgcn_exp2f(st[r]);
                    if (!nomask) {
                        const int tg = k0 + tf * 32 + (r & 3) + 8 * (r >> 2) + 4 * hi;
                        if (tg > qg) e = 0.f;
                    }
                    p[r] = e;
                    lsum += e;
                }
                // direct pack: A-slot j of chunk ks=2tf+m <- p[8m+j] (sigma'd V aligns)
                #pragma unroll
                for (int m = 0; m < 2; m++) {
                    union { unsigned d[4]; bf16x8 v; } pk;
                    #pragma unroll
                    for (int dw = 0; dw < 4; dw++)
                        pk.d[dw] = packbf(p[8 * m + 2 * dw], p[8 * m + 2 * dw + 1]);
                    pa[tf * 2 + m] = pk.v;
                }
            }
            // PV: Y += P @ V_tile (swizzled LDS)
            #pragma unroll
            for (int ks = 0; ks < 4; ks++) {
                const int cs = (ks * 2 + hi) ^ swz;
                #pragma unroll
                for (int df = 0; df < 2; df++) {
                    bf16x8 vf = *(const bf16x8*)((const char*)&Vs[buf][0] + (df * 32 + l31) * 128 + cs * 16);
                    yacc[df] = __builtin_amdgcn_mfma_f32_32x32x16_bf16(pa[ks], vf, yacc[df], 0, 0, 0);
                }
            }
        }
    }
    __syncthreads();

    // combine the two k-halves (hi 0/1) of each q-row sum, publish per-wave
    lsum += __shfl_xor(lsum, 32);
    if (hi == 0) Ls[w * 32 + l31] = lsum;
    __syncthreads();

    #pragma unroll
    for (int g = 0; g < 4; g++) {
        float4 lv = *(const float4*)&Ls[w * 32 + g * 8 + hi * 4];
        #pragma unroll
        for (int df = 0; df < 2; df++)
            #pragma unroll
            for (int rr = 0; rr < 4; rr++) {
                const float v = yacc[df][g * 4 + rr] / ((const float*)&lv)[rr];
                const size_t row = (size_t)(b * TSEQ + qw + 8 * g + 4 * hi + rr);
                Y[row * CDIM + h * HS + df * 32 + l31] = __float2bfloat16(v);
            }
    }
}

extern "C" void kernel_launch(void* const* d_in, const int* in_sizes, int n_in,
                              void* d_out, int out_size, void* d_ws, size_t ws_size,
                              hipStream_t stream) {
    const float* x   = (const float*)d_in[0];
    const float* W1  = (const float*)d_in[1];
    const float* bw1 = (const float*)d_in[2];
    const float* b1  = (const float*)d_in[3];
    const float* w2  = (const float*)d_in[4];
    const float* b2  = (const float*)d_in[5];
    const float* Wv  = (const float*)d_in[6];
    const float* bv  = (const float*)d_in[7];
    const float* Wp  = (const float*)d_in[8];
    const float* bp  = (const float*)d_in[9];
    float* out = (float*)d_out;

    const int B = in_sizes[0] / (TSEQ * CDIM);   // 2
    const int M = B * TSEQ;                      // 4096
    const size_t MC = (size_t)M * CDIM;          // 4M
    const size_t WC = (size_t)CDIM * CDIM;       // 1M

    __hip_bfloat16* xb  = (__hip_bfloat16*)d_ws;
    __hip_bfloat16* Wqv = xb  + MC;              // [2048][1024]: W1t then Wvt
    __hip_bfloat16* Wpt = Wqv + 2 * WC;
    __hip_bfloat16* w2t = Wpt + WC;              // [T][HS]
    __hip_bfloat16* Hb  = w2t + (size_t)TSEQ * HS;
    __hip_bfloat16* Vbk = Hb  + MC;              // blocked [h][b][kt][d][64]
    __hip_bfloat16* Yb  = Vbk + MC;
    float*          bl  = (float*)(Yb + MC);     // b2*log2e, T floats

    dim3 blk(256);
    conv_bf16<<<dim3((unsigned)(MC / 1024)), blk, 0, stream>>>(x, xb, (int)MC);
    b2_log2e<<<dim3(TSEQ / 256), blk, 0, stream>>>(b2, bl, TSEQ);
    transpose3_to_bf16<<<dim3(32, 32, 3), blk, 0, stream>>>(W1, Wv, Wp, Wqv, Wqv + WC, Wpt);
    transpose_to_bf16<<<dim3(TSEQ / 32, HS / 32), blk, 0, stream>>>(w2, w2t, HS, TSEQ);

    gemm_qv<<<dim3(16, M / 128), blk, 0, stream>>>(xb, Wqv, bw1, b1, bv, Hb, Vbk, M);

    attn_mfma19<<<dim3(8, NH, B), dim3(512), 0, stream>>>(Hb, w2t, Vbk, bl, Yb, M);

    gemm_proj<<<dim3(8, M / 128), blk, 0, stream>>>(Yb, Wpt, bp, out, M);
}

// Round 24
// 110.923 us; speedup vs baseline: 1.2311x; 1.2311x over previous
//
#include <hip/hip_runtime.h>
#include <hip/hip_bf16.h>

#define TSEQ 2048
#define CDIM 1024
#define NH 16
#define HS 64

typedef __attribute__((ext_vector_type(8))) short bf16x8;
typedef __attribute__((ext_vector_type(4))) float f32x4;
typedef __attribute__((ext_vector_type(16))) float f32x16;

__device__ inline void gload16(const void* g, void* l) {
    __builtin_amdgcn_global_load_lds((const __attribute__((address_space(1))) void*)g,
                                     (__attribute__((address_space(3))) void*)l, 16, 0, 0);
}
__device__ inline void gload4(const void* g, void* l) {
    __builtin_amdgcn_global_load_lds((const __attribute__((address_space(1))) void*)g,
                                     (__attribute__((address_space(3))) void*)l, 4, 0, 0);
}

__device__ inline unsigned packbf(float a, float b) {
    union { __hip_bfloat162 h; unsigned u; } cv;
    cv.h = __float22bfloat162_rn(make_float2(a, b));
    return cv.u;
}

// ---------- fused preprocessing: conv(x), transpose W1/Wv/Wp, transpose w2,
// b2*log2e — one launch, block-index-range dispatch (all independent work) ----
__global__ __launch_bounds__(256)
void prep(const float* __restrict__ x, __hip_bfloat16* __restrict__ xb, int nx,
          const float* __restrict__ W1, const float* __restrict__ Wv,
          const float* __restrict__ Wp, __hip_bfloat16* __restrict__ o1,
          __hip_bfloat16* __restrict__ o2, __hip_bfloat16* __restrict__ o3,
          const float* __restrict__ w2, __hip_bfloat16* __restrict__ w2t,
          const float* __restrict__ b2, float* __restrict__ bl,
          int nconv, int nt3, int nw2)
{
    __shared__ float t[32][33];
    const int bid = blockIdx.x;
    const int tid = threadIdx.x;

    if (bid < nconv) {                       // ---- x -> bf16 (4 elems/thread)
        int i = (bid * 256 + tid) * 4;
        if (i + 3 < nx) {
            float4 v = *(const float4*)(x + i);
            union { ushort4 u; __hip_bfloat16 h[4]; } o;
            o.h[0] = __float2bfloat16(v.x);
            o.h[1] = __float2bfloat16(v.y);
            o.h[2] = __float2bfloat16(v.z);
            o.h[3] = __float2bfloat16(v.w);
            *(ushort4*)((unsigned short*)xb + i) = o.u;
        }
    } else if (bid < nconv + nt3) {          // ---- 3x 1024^2 weight transpose
        const int idx = bid - nconv;
        const int z = idx >> 10;             // 0..2  (1024 tiles per matrix)
        const int rest = idx & 1023;
        const int by = rest >> 5, bx = rest & 31;
        const float* in = z == 0 ? W1 : (z == 1 ? Wv : Wp);
        __hip_bfloat16* out = z == 0 ? o1 : (z == 1 ? o2 : o3);
        const int tx = tid & 31, ty = tid >> 5;
        const int r0 = by * 32, c0 = bx * 32;
        #pragma unroll
        for (int i = 0; i < 32; i += 8)
            t[ty + i][tx] = in[(size_t)(r0 + ty + i) * CDIM + c0 + tx];
        __syncthreads();
        #pragma unroll
        for (int i = 0; i < 32; i += 8)
            out[(size_t)(c0 + ty + i) * CDIM + r0 + tx] = __float2bfloat16(t[tx][ty + i]);
    } else if (bid < nconv + nt3 + nw2) {    // ---- w2 [HS][T] -> w2t [T][HS]
        const int idx = bid - nconv - nt3;
        const int bx = idx & 63, by = idx >> 6;      // grid (64, 2)
        const int tx = tid & 31, ty = tid >> 5;
        const int r0 = by * 32, c0 = bx * 32;        // rows over HS, cols over T
        #pragma unroll
        for (int i = 0; i < 32; i += 8)
            t[ty + i][tx] = w2[(size_t)(r0 + ty + i) * TSEQ + c0 + tx];
        __syncthreads();
        #pragma unroll
        for (int i = 0; i < 32; i += 8)
            w2t[(size_t)(c0 + ty + i) * HS + r0 + tx] = __float2bfloat16(t[tx][ty + i]);
    } else {                                 // ---- b2 * log2e
        const int i = (bid - nconv - nt3 - nw2) * 256 + tid;
        if (i < TSEQ) bl[i] = b2[i] * 1.44269504f;
    }
}

// ---------- fused QV GEMM: [H | Vblk] = x @ [W1 | Wv] ----------
// H scaled by log2(e) so attention can use native exp2 directly.
// V written to BLOCKED layout Vblk[h][b][kt][d][64] with sigma (swap t-bits
// 2,3) applied within each 64-panel so the attention kernel's PV B-operand
// lines up with direct-packed P fragments (no shfl).
__global__ __launch_bounds__(256, 2)
void gemm_qv(const __hip_bfloat16* __restrict__ X, const __hip_bfloat16* __restrict__ W,
             const float* __restrict__ bw1, const float* __restrict__ b1,
             const float* __restrict__ bv, __hip_bfloat16* __restrict__ Hb,
             __hip_bfloat16* __restrict__ Vblk, int M)
{
    __shared__ __align__(16) __hip_bfloat16 As[128 * 32];
    __shared__ __align__(16) __hip_bfloat16 Bs[128 * 32];
    const int tid = threadIdx.x, wave = tid >> 6, lane = tid & 63;
    const int wr = wave >> 1, wc = wave & 1, l15 = lane & 15, l4 = lane >> 4;
    const int m0 = blockIdx.y * 128, n0 = blockIdx.x * 128;
    const int K = CDIM;
    const int Bb = M >> 11;                       // batches (T=2048)
    const int srow = wave * 32 + (lane >> 2), scol = (lane & 3) * 8;
    const __hip_bfloat16* xg = X + (size_t)(m0 + srow) * K + scol;
    const __hip_bfloat16* wg = W + (size_t)(n0 + srow) * K + scol;
    __hip_bfloat16* la = &As[wave * 32 * 32];
    __hip_bfloat16* lb = &Bs[wave * 32 * 32];

    f32x4 acc[4][4] = {};
    for (int k0 = 0; k0 < K; k0 += 32) {
        __syncthreads();
        gload16(xg + k0, la);
        gload16(xg + k0 + (size_t)16 * K, la + 16 * 32);
        gload16(wg + k0, lb);
        gload16(wg + k0 + (size_t)16 * K, lb + 16 * 32);
        __syncthreads();
        bf16x8 af[4], bfr[4];
        #pragma unroll
        for (int f = 0; f < 4; f++) af[f]  = *(const bf16x8*)&As[(wr * 64 + f * 16 + l15) * 32 + l4 * 8];
        #pragma unroll
        for (int f = 0; f < 4; f++) bfr[f] = *(const bf16x8*)&Bs[(wc * 64 + f * 16 + l15) * 32 + l4 * 8];
        #pragma unroll
        for (int fr = 0; fr < 4; fr++)
            #pragma unroll
            for (int fc = 0; fc < 4; fc++)
                acc[fr][fc] = __builtin_amdgcn_mfma_f32_16x16x32_bf16(af[fr], bfr[fc], acc[fr][fc], 0, 0, 0);
    }

    const bool isH = (n0 < CDIM);
    const int sl4 = ((l4 & 1) << 1) | (l4 >> 1);   // sigma: swap t-bits 2,3
    if (isH) {
        #pragma unroll
        for (int fc = 0; fc < 4; fc++) {
            const int col = n0 + wc * 64 + fc * 16 + l15;
            const float bias = bw1[col] + b1[col & (HS - 1)];
            #pragma unroll
            for (int fr = 0; fr < 4; fr++)
                #pragma unroll
                for (int r = 0; r < 4; r++) {
                    const int row = m0 + wr * 64 + fr * 16 + l4 * 4 + r;
                    const float hv = fmaxf(acc[fr][fc][r] + bias, 0.f) * 1.44269504f;
                    Hb[(size_t)row * CDIM + col] = __float2bfloat16(hv);
                }
        }
    } else {
        const int mt = m0 + wr * 64;
        const int bb = mt >> 11;                   // batch
        const int ktb = (mt & (TSEQ - 1)) >> 6;    // k-tile index
        const int hh = ((n0 - CDIM) + wc * 64) >> 6;  // head
        __hip_bfloat16* tile = Vblk + (((size_t)hh * Bb + bb) * (TSEQ / 64) + ktb) * (HS * 64);
        #pragma unroll
        for (int fc = 0; fc < 4; fc++) {
            const int d = fc * 16 + l15;
            const int c2 = hh * HS + d;
            const float bias = bv[c2];
            #pragma unroll
            for (int fr = 0; fr < 4; fr++) {
                const int tl = fr * 16 + sl4 * 4;  // sigma'd t within panel
                union { ushort4 u; __hip_bfloat16 h[4]; } o;
                #pragma unroll
                for (int r = 0; r < 4; r++) o.h[r] = __float2bfloat16(acc[fr][fc][r] + bias);
                *(ushort4*)(tile + (size_t)d * 64 + tl) = o.u;
            }
        }
    }
}

// ---------- projection GEMM: out = Y @ Wp + bp (f32 out) ----------
__global__ __launch_bounds__(256, 2)
void gemm_proj(const __hip_bfloat16* __restrict__ X, const __hip_bfloat16* __restrict__ Wt,
               const float* __restrict__ bN, float* __restrict__ Out, int M)
{
    __shared__ __align__(16) __hip_bfloat16 As[128 * 32];
    __shared__ __align__(16) __hip_bfloat16 Bs[128 * 32];
    const int tid = threadIdx.x, wave = tid >> 6, lane = tid & 63;
    const int wr = wave >> 1, wc = wave & 1, l15 = lane & 15, l4 = lane >> 4;
    const int m0 = blockIdx.y * 128, n0 = blockIdx.x * 128;
    const int K = CDIM;
    const int srow = wave * 32 + (lane >> 2), scol = (lane & 3) * 8;
    const __hip_bfloat16* xg = X + (size_t)(m0 + srow) * K + scol;
    const __hip_bfloat16* wg = Wt + (size_t)(n0 + srow) * K + scol;
    __hip_bfloat16* la = &As[wave * 32 * 32];
    __hip_bfloat16* lb = &Bs[wave * 32 * 32];

    f32x4 acc[4][4] = {};
    for (int k0 = 0; k0 < K; k0 += 32) {
        __syncthreads();
        gload16(xg + k0, la);
        gload16(xg + k0 + (size_t)16 * K, la + 16 * 32);
        gload16(wg + k0, lb);
        gload16(wg + k0 + (size_t)16 * K, lb + 16 * 32);
        __syncthreads();
        bf16x8 af[4], bfr[4];
        #pragma unroll
        for (int f = 0; f < 4; f++) af[f]  = *(const bf16x8*)&As[(wr * 64 + f * 16 + l15) * 32 + l4 * 8];
        #pragma unroll
        for (int f = 0; f < 4; f++) bfr[f] = *(const bf16x8*)&Bs[(wc * 64 + f * 16 + l15) * 32 + l4 * 8];
        #pragma unroll
        for (int fr = 0; fr < 4; fr++)
            #pragma unroll
            for (int fc = 0; fc < 4; fc++)
                acc[fr][fc] = __builtin_amdgcn_mfma_f32_16x16x32_bf16(af[fr], bfr[fc], acc[fr][fc], 0, 0, 0);
    }

    #pragma unroll
    for (int fc = 0; fc < 4; fc++) {
        const int col = n0 + wc * 64 + fc * 16 + l15;
        const float bias = bN[col];
        #pragma unroll
        for (int fr = 0; fr < 4; fr++)
            #pragma unroll
            for (int r = 0; r < 4; r++) {
                const int row = m0 + wr * 64 + fr * 16 + l4 * 4 + r;
                Out[(size_t)row * CDIM + col] = acc[fr][fc][r] + bias;
            }
    }
}

// ---------- fused synthesizer attention v18 (best: r22, 57.4 us) ----------
// KVBLK=128, ring-2, stage-after-barrier, counted vmcnt(0)-at-distance;
// per-subtile-parity accumulators break cross-subtile serial chains; direct
// sigma P-pack; native exp2 with bias folded into MFMA C-init.
#define STAGE2(KT2, BUF) do {                                                   \
    const size_t tA_ = (size_t)(2 * (KT2)) * (64 * HS);                         \
    const size_t tB_ = (size_t)(2 * (KT2) + 1) * (64 * HS);                     \
    gload16(kg0 + tA_, &Ks[BUF][0][(w * 16) * 64]);                             \
    gload16(kg1 + tA_, &Ks[BUF][0][(w * 16 + 8) * 64]);                         \
    gload16(kg0 + tB_, &Ks[BUF][1][(w * 16) * 64]);                             \
    gload16(kg1 + tB_, &Ks[BUF][1][(w * 16 + 8) * 64]);                         \
    gload16(vg0 + tA_, &Vs[BUF][0][(w * 16) * 64]);                             \
    gload16(vg1 + tA_, &Vs[BUF][0][(w * 16 + 8) * 64]);                         \
    gload16(vg0 + tB_, &Vs[BUF][1][(w * 16) * 64]);                             \
    gload16(vg1 + tB_, &Vs[BUF][1][(w * 16 + 8) * 64]);                         \
    gload4(blg + (size_t)(KT2) * 128, &blr[BUF][0]);                            \
    gload4(blg + (size_t)(KT2) * 128 + 64, &blr[BUF][64]);                      \
} while (0)

__global__ __launch_bounds__(256, 2)
void attn_mfma18(const __hip_bfloat16* __restrict__ H, const __hip_bfloat16* __restrict__ w2t,
                 const __hip_bfloat16* __restrict__ Vblk, const float* __restrict__ bl,
                 __hip_bfloat16* __restrict__ Y, int M)
{
    __shared__ __align__(16) __hip_bfloat16 Ks[2][2][64 * 64];  // [buf][sub][t][hs]
    __shared__ __align__(16) __hip_bfloat16 Vs[2][2][64 * 64];  // [buf][sub][d][t sigma]
    __shared__ __align__(16) float blr[2][128];                 // bias ring (1KB)
    __shared__ float Ls[4 * 32];

    const int tid = threadIdx.x;
    const int w = tid >> 6, lane = tid & 63;
    const int l31 = lane & 31, hi = lane >> 5;
    const int h = blockIdx.y, b = blockIdx.z;
    const int u = (blockIdx.x + blockIdx.y) & 15;
    const int qb = b ? (15 - u) : u;        // causal load-balance pairing
    const int q0 = qb * 128;
    const int qw = q0 + w * 32;             // this wave's first q row
    const int swz = l31 & 7;
    const int Bb = M >> 11;

    // staging geometry: wave w stages rows w*16 .. w*16+15 of each 64-tile
    const int srr = lane >> 3, spc = lane & 7;
    const int sr0 = w * 16 + srr, sr1 = sr0 + 8;
    const int sc = (spc ^ srr) * 8;          // pre-XOR source chunk ((sr&7)==srr)
    const __hip_bfloat16* kg0 = w2t + (size_t)sr0 * HS + sc;
    const __hip_bfloat16* kg1 = w2t + (size_t)sr1 * HS + sc;
    const __hip_bfloat16* vpan = Vblk + (((size_t)h * Bb + b) * (TSEQ / 64)) * (HS * 64);
    const __hip_bfloat16* vg0 = vpan + (size_t)sr0 * 64 + sc;
    const __hip_bfloat16* vg1 = vpan + (size_t)sr1 * 64 + sc;
    const float* blg = bl + lane;            // per-lane f32 source (width-4 stage)

    // H fragments (B-operand: col=lane&31=q, k=hi*8+j), in registers
    bf16x8 hf[4];
    {
        const size_t row = (size_t)(b * TSEQ + qw + l31);
        #pragma unroll
        for (int kk = 0; kk < 4; kk++)
            hf[kk] = *(const bf16x8*)(H + row * CDIM + h * HS + kk * 16 + hi * 8);
    }

    f32x16 yA[2] = {};   // subtile-parity 0 accumulators
    f32x16 yB[2] = {};   // subtile-parity 1 accumulators
    float lsA = 0.f, lsB = 0.f;
    const int ntile2 = qb + 1;               // 128-wide k-blocks

    STAGE2(0, 0);

    for (int kt2 = 0; kt2 < ntile2; kt2++) {
        asm volatile("s_waitcnt vmcnt(0)" ::: "memory");   // own S(kt2) landed
        __builtin_amdgcn_s_barrier();                      // all waves' S(kt2) landed
        __builtin_amdgcn_sched_barrier(0);
        if (kt2 + 1 < ntile2) STAGE2(kt2 + 1, (kt2 + 1) & 1);  // overlaps compute
        const int buf = kt2 & 1;
        #pragma unroll
        for (int sub = 0; sub < 2; sub++) {
            const int k0 = kt2 * 128 + sub * 64;
            if (k0 > qw + 31) continue;
            const bool nomask = (k0 + 63 <= qw);
            f32x16* yacc = sub ? yB : yA;
            bf16x8 pa[4];
            float lloc = 0.f;
            #pragma unroll
            for (int tf = 0; tf < 2; tf++) {
                // C-init = bias*log2e from the ring (broadcast, conflict-free)
                f32x16 st;
                #pragma unroll
                for (int g = 0; g < 4; g++) {
                    float4 blv = *(const float4*)&blr[buf][sub * 64 + tf * 32 + g * 8 + hi * 4];
                    st[g * 4 + 0] = blv.x; st[g * 4 + 1] = blv.y;
                    st[g * 4 + 2] = blv.z; st[g * 4 + 3] = blv.w;
                }
                #pragma unroll
                for (int kk = 0; kk < 4; kk++) {
                    const int cs = (kk * 2 + hi) ^ swz;
                    bf16x8 kf = *(const bf16x8*)((const char*)&Ks[buf][sub][0] + (tf * 32 + l31) * 128 + cs * 16);
                    st = __builtin_amdgcn_mfma_f32_32x32x16_bf16(kf, hf[kk], st, 0, 0, 0);
                }
                const int qg = qw + l31;
                float p[16];
                float t0 = 0.f, t1 = 0.f;    // split lsum chain
                #pragma unroll
                for (int r = 0; r < 16; r++) {
                    float e = __builtin_amdgcn_exp2f(st[r]);
                    if (!nomask) {
                        const int tg = k0 + tf * 32 + (r & 3) + 8 * (r >> 2) + 4 * hi;
                        if (tg > qg) e = 0.f;
                    }
                    p[r] = e;
                    if (r & 1) t1 += e; else t0 += e;
                }
                lloc += t0 + t1;
                // direct pack: A-slot j of chunk ks=2tf+m <- p[8m+j] (sigma'd V aligns)
                #pragma unroll
                for (int m = 0; m < 2; m++) {
                    union { unsigned d[4]; bf16x8 v; } pk;
                    #pragma unroll
                    for (int dw = 0; dw < 4; dw++)
                        pk.d[dw] = packbf(p[8 * m + 2 * dw], p[8 * m + 2 * dw + 1]);
                    pa[tf * 2 + m] = pk.v;
                }
            }
            if (sub) lsB += lloc; else lsA += lloc;
            // PV: Y_sub += P @ V_subtile (independent accumulator per parity)
            #pragma unroll
            for (int ks = 0; ks < 4; ks++) {
                const int cs = (ks * 2 + hi) ^ swz;
                #pragma unroll
                for (int df = 0; df < 2; df++) {
                    bf16x8 vf = *(const bf16x8*)((const char*)&Vs[buf][sub][0] + (df * 32 + l31) * 128 + cs * 16);
                    yacc[df] = __builtin_amdgcn_mfma_f32_32x32x16_bf16(pa[ks], vf, yacc[df], 0, 0, 0);
                }
            }
        }
    }
    __syncthreads();

    // combine parity accumulators, then the two k-halves (hi 0/1) per q-row
    float lsum = lsA + lsB;
    f32x16 yacc[2];
    yacc[0] = yA[0] + yB[0];
    yacc[1] = yA[1] + yB[1];

    lsum += __shfl_xor(lsum, 32);
    if (hi == 0) Ls[w * 32 + l31] = lsum;
    __syncthreads();

    #pragma unroll
    for (int g = 0; g < 4; g++) {
        float4 lv = *(const float4*)&Ls[w * 32 + g * 8 + hi * 4];
        #pragma unroll
        for (int df = 0; df < 2; df++)
            #pragma unroll
            for (int rr = 0; rr < 4; rr++) {
                const float v = yacc[df][g * 4 + rr] / ((const float*)&lv)[rr];
                const size_t row = (size_t)(b * TSEQ + qw + 8 * g + 4 * hi + rr);
                Y[row * CDIM + h * HS + df * 32 + l31] = __float2bfloat16(v);
            }
    }
}

extern "C" void kernel_launch(void* const* d_in, const int* in_sizes, int n_in,
                              void* d_out, int out_size, void* d_ws, size_t ws_size,
                              hipStream_t stream) {
    const float* x   = (const float*)d_in[0];
    const float* W1  = (const float*)d_in[1];
    const float* bw1 = (const float*)d_in[2];
    const float* b1  = (const float*)d_in[3];
    const float* w2  = (const float*)d_in[4];
    const float* b2  = (const float*)d_in[5];
    const float* Wv  = (const float*)d_in[6];
    const float* bv  = (const float*)d_in[7];
    const float* Wp  = (const float*)d_in[8];
    const float* bp  = (const float*)d_in[9];
    float* out = (float*)d_out;

    const int B = in_sizes[0] / (TSEQ * CDIM);   // 2
    const int M = B * TSEQ;                      // 4096
    const size_t MC = (size_t)M * CDIM;          // 4M
    const size_t WC = (size_t)CDIM * CDIM;       // 1M

    __hip_bfloat16* xb  = (__hip_bfloat16*)d_ws;
    __hip_bfloat16* Wqv = xb  + MC;              // [2048][1024]: W1t then Wvt
    __hip_bfloat16* Wpt = Wqv + 2 * WC;
    __hip_bfloat16* w2t = Wpt + WC;              // [T][HS]
    __hip_bfloat16* Hb  = w2t + (size_t)TSEQ * HS;
    __hip_bfloat16* Vbk = Hb  + MC;              // blocked [h][b][kt][d][64]
    __hip_bfloat16* Yb  = Vbk + MC;
    float*          bl  = (float*)(Yb + MC);     // b2*log2e, T floats

    const int nconv = (int)(MC / 1024);          // 4096
    const int nt3   = 32 * 32 * 3;               // 3072
    const int nw2   = (TSEQ / 32) * (HS / 32);   // 128
    const int nb2   = TSEQ / 256;                // 8

    dim3 blk(256);
    prep<<<dim3(nconv + nt3 + nw2 + nb2), blk, 0, stream>>>(
        x, xb, (int)MC, W1, Wv, Wp, Wqv, Wqv + WC, Wpt, w2, w2t, b2, bl,
        nconv, nt3, nw2);

    gemm_qv<<<dim3(16, M / 128), blk, 0, stream>>>(xb, Wqv, bw1, b1, bv, Hb, Vbk, M);

    attn_mfma18<<<dim3(16, NH, B), blk, 0, stream>>>(Hb, w2t, Vbk, bl, Yb, M);

    gemm_proj<<<dim3(8, M / 128), blk, 0, stream>>>(Yb, Wpt, bp, out, M);
}